// Round 12
// baseline (113.734 us; speedup 1.0000x reference)
//
#include <hip/hip_runtime.h>

// KDA delta-rule state update, B=H=32, K=V=256, fp32.
// out[k,v] = g[k]*S[k,v] + cb[k]*(val[v] - kt[v]),
//   w[k] = g[k]*key[k], cb[k] = beta*key[k], kt[v] = sum_k w[k]*S[k,v].
//
// R12: split-K pair-wave variant of R10. Block = 128 threads (2 waves).
// Wave wv owns rows [128wv, 128wv+128); lane (r8,c8) holds 16 rows x one
// f32x4 col = 64 data VGPRs (half of R10 -> ~2x occupancy, 16+ waves/CU).
// Loads/stores remain 128B-chunk coalesced (8 lanes x 16B per row).
// kt: in-lane over 16 rows + 3-round shfl_xor over r8 + ONE 256B LDS
// exchange between the 2 waves (lgkm-only barrier). High TLP (the R8-k2
// 6.1 TB/s regime) + single-pass register residency.

#define KD 256
#define VD 256
#define VD4 (VD / 4)   // 64 f32x4 per row

typedef float f32x4 __attribute__((ext_vector_type(4)));

// barrier that drains LDS ops only -- in-flight global loads/stores survive
__device__ __forceinline__ void lds_barrier() {
    asm volatile("s_waitcnt lgkmcnt(0)" ::: "memory");
    __builtin_amdgcn_s_barrier();
}

__global__ __launch_bounds__(128, 4)
void kda_update_kernel(const float* __restrict__ state,
                       const float* __restrict__ keys,
                       const float* __restrict__ values,
                       const float* __restrict__ gates,
                       const float* __restrict__ beta,
                       float* __restrict__ out)
{
    const int bid = blockIdx.x;
    const int bh  = bid >> 3;            // (b,h) tile
    const int cg  = bid & 7;             // column group (8 f32x4 cols each)
    const size_t toff = (size_t)bh * (KD * VD);
    const f32x4* __restrict__ S4 = (const f32x4*)(state + toff);
    f32x4* __restrict__ O4 = (f32x4*)(out + toff);

    __shared__ float s_g[KD];        // alpha
    __shared__ float s_w[KD];        // alpha*key
    __shared__ float s_c[KD];        // beta*key
    __shared__ f32x4 s_x[2][8];      // per-wave kt partials (256 B)

    const int t    = threadIdx.x;
    const int wv   = t >> 6;             // wave 0/1
    const int lane = t & 63;
    const int r8   = lane >> 3;          // row residue 0..7
    const int c8   = lane & 7;           // col within group
    const int col  = cg * 8 + c8;        // lane's f32x4 column
    const int rbase = wv * 128;          // wave's row range start

    // ---- stage per-row scalars (128 threads x 2 rows each) ----
#pragma unroll
    for (int i = 0; i < 2; ++i) {
        const int r = t + 128 * i;
        const float g = gates[bh * KD + r];
        const float k = keys[bh * KD + r];
        s_g[r] = g;
        s_w[r] = g * k;
        s_c[r] = beta[bh] * k;
    }
    lds_barrier();

    // ---- load this wave's 128 rows x lane's column (16 f32x4) ----
    f32x4 s[16];
#pragma unroll
    for (int j = 0; j < 16; ++j)
        s[j] = __builtin_nontemporal_load(&S4[(size_t)(rbase + r8 + 8 * j) * VD4 + col]);

    // ---- in-lane kt partial over 16 rows ----
    f32x4 p = (f32x4)(0.f);
#pragma unroll
    for (int j = 0; j < 16; ++j) {
        const float w = s_w[rbase + r8 + 8 * j];   // broadcast over c8
        p.x = fmaf(w, s[j].x, p.x);
        p.y = fmaf(w, s[j].y, p.y);
        p.z = fmaf(w, s[j].z, p.z);
        p.w = fmaf(w, s[j].w, p.w);
    }

    // ---- in-wave butterfly over r8 (lane bits 3..5) ----
#pragma unroll
    for (int m = 8; m <= 32; m <<= 1) {
        p.x += __shfl_xor(p.x, m, 64);
        p.y += __shfl_xor(p.y, m, 64);
        p.z += __shfl_xor(p.z, m, 64);
        p.w += __shfl_xor(p.w, m, 64);
    }

    // ---- cross-wave combine: one 128B write per wave + barrier ----
    if (lane < 8) s_x[wv][lane] = p;     // lane==c8 for lane<8
    lds_barrier();
    {
        const f32x4 q = s_x[wv ^ 1][c8];
        p.x += q.x; p.y += q.y; p.z += q.z; p.w += q.w;
    }

    const f32x4 vv = ((const f32x4*)(values + (size_t)bh * VD))[col];
    f32x4 d;
    d.x = vv.x - p.x; d.y = vv.y - p.y;
    d.z = vv.z - p.z; d.w = vv.w - p.w;

    // ---- output: same rows, straight from registers ----
#pragma unroll
    for (int j = 0; j < 16; ++j) {
        const int r = rbase + r8 + 8 * j;
        const float g  = s_g[r];
        const float cb = s_c[r];
        f32x4 o;
        o.x = fmaf(g, s[j].x, cb * d.x);
        o.y = fmaf(g, s[j].y, cb * d.y);
        o.z = fmaf(g, s[j].z, cb * d.z);
        o.w = fmaf(g, s[j].w, cb * d.w);
        __builtin_nontemporal_store(o, &O4[(size_t)r * VD4 + col]);
    }
}

extern "C" void kernel_launch(void* const* d_in, const int* in_sizes, int n_in,
                              void* d_out, int out_size, void* d_ws, size_t ws_size,
                              hipStream_t stream) {
    const float* state  = (const float*)d_in[0];
    const float* keys   = (const float*)d_in[1];
    const float* values = (const float*)d_in[2];
    const float* gates  = (const float*)d_in[3];
    const float* beta   = (const float*)d_in[4];
    float* out = (float*)d_out;

    dim3 grid(32 * 32 * 8);   // (b,h) x 8 column groups
    dim3 block(128);          // 2 waves
    hipLaunchKernelGGL(kda_update_kernel, grid, block, 0, stream,
                       state, keys, values, gates, beta, out);
}

// Round 13
// 97.013 us; speedup vs baseline: 1.1724x; 1.1724x over previous
//
#include <hip/hip_runtime.h>

// KDA delta-rule state update, B=H=32, K=V=256, fp32.
// out[k,v] = g[k]*S[k,v] + cb[k]*(val[v] - kt[v]),
//   w[k] = g[k]*key[k], cb[k] = beta*key[k], kt[v] = sum_k w[k]*S[k,v].
//
// R13 = R10's wave-autonomous structure UNCHANGED (lane (r8,c8) owns 32
// rows x one f32x4 col = 128 data VGPRs; 128B chunks; in-wave butterfly
// kt; no barriers in main body) with launch_bounds min-waves/EU raised
// 2 -> 3: caps VGPR at 170 so 3 waves/SIMD (12 waves/CU) fit, +50% TLP.
// Output computed in-place into s[j] to shorten live ranges for the
// tighter register budget.

#define KD 256
#define VD 256
#define VD4 (VD / 4)   // 64 f32x4 per row

typedef float f32x4 __attribute__((ext_vector_type(4)));

__global__ __launch_bounds__(256, 3)
void kda_update_kernel(const float* __restrict__ state,
                       const float* __restrict__ keys,
                       const float* __restrict__ values,
                       const float* __restrict__ gates,
                       const float* __restrict__ beta,
                       float* __restrict__ out)
{
    const int bid  = blockIdx.x;
    const int bh   = bid >> 1;          // (b,h) tile
    const int half = bid & 1;           // V half (cols 0-127 / 128-255)
    const size_t toff = (size_t)bh * (KD * VD);
    const f32x4* __restrict__ S4 = (const f32x4*)(state + toff);
    f32x4* __restrict__ O4 = (f32x4*)(out + toff);

    __shared__ float s_g[KD];   // alpha
    __shared__ float s_w[KD];   // alpha*key
    __shared__ float s_c[KD];   // beta*key

    const int t    = threadIdx.x;
    const int wv   = t >> 6;            // wave 0..3
    const int lane = t & 63;
    const int r8   = lane >> 3;         // row residue 0..7
    const int c8   = lane & 7;          // f32x4 col within wave's 8
    const int col  = half * 32 + wv * 8 + c8;   // this lane's f32x4 column

    // ---- stage per-row scalars once (the only block-wide coupling) ----
    {
        const float g = gates[bh * KD + t];
        const float k = keys[bh * KD + t];
        s_g[t] = g;
        s_w[t] = g * k;
        s_c[t] = beta[bh] * k;
    }
    __syncthreads();

    // ---- load all 256 rows' worth of this lane's column (32 f32x4) ----
    f32x4 s[32];
#pragma unroll
    for (int j = 0; j < 32; ++j)
        s[j] = __builtin_nontemporal_load(&S4[(size_t)(r8 + 8 * j) * VD4 + col]);

    // ---- in-lane kt partial over this lane's 32 rows ----
    f32x4 p = (f32x4)(0.f);
#pragma unroll
    for (int j = 0; j < 32; ++j) {
        const float w = s_w[r8 + 8 * j];   // broadcast over c8
        p.x = fmaf(w, s[j].x, p.x);
        p.y = fmaf(w, s[j].y, p.y);
        p.z = fmaf(w, s[j].z, p.z);
        p.w = fmaf(w, s[j].w, p.w);
    }

    // ---- in-wave reduce over r8 (lane bits 3,4,5): 3 butterfly rounds ----
#pragma unroll
    for (int m = 8; m <= 32; m <<= 1) {
        p.x += __shfl_xor(p.x, m, 64);
        p.y += __shfl_xor(p.y, m, 64);
        p.z += __shfl_xor(p.z, m, 64);
        p.w += __shfl_xor(p.w, m, 64);
    }

    const f32x4 vv = ((const f32x4*)(values + (size_t)bh * VD))[col];
    f32x4 d;
    d.x = vv.x - p.x; d.y = vv.y - p.y;
    d.z = vv.z - p.z; d.w = vv.w - p.w;

    // ---- output in-place (shorter live ranges), then store ----
#pragma unroll
    for (int j = 0; j < 32; ++j) {
        const int r = r8 + 8 * j;
        const float g  = s_g[r];
        const float cb = s_c[r];
        s[j].x = fmaf(g, s[j].x, cb * d.x);
        s[j].y = fmaf(g, s[j].y, cb * d.y);
        s[j].z = fmaf(g, s[j].z, cb * d.z);
        s[j].w = fmaf(g, s[j].w, cb * d.w);
        __builtin_nontemporal_store(s[j], &O4[(size_t)r * VD4 + col]);
    }
}

extern "C" void kernel_launch(void* const* d_in, const int* in_sizes, int n_in,
                              void* d_out, int out_size, void* d_ws, size_t ws_size,
                              hipStream_t stream) {
    const float* state  = (const float*)d_in[0];
    const float* keys   = (const float*)d_in[1];
    const float* values = (const float*)d_in[2];
    const float* gates  = (const float*)d_in[3];
    const float* beta   = (const float*)d_in[4];
    float* out = (float*)d_out;

    dim3 grid(32 * 32 * 2);   // (b,h) x 2 V-halves
    dim3 block(256);
    hipLaunchKernelGGL(kda_update_kernel, grid, block, 0, stream,
                       state, keys, values, gates, beta, out);
}

// Round 14
// 96.721 us; speedup vs baseline: 1.1759x; 1.0030x over previous
//
#include <hip/hip_runtime.h>

// KDA delta-rule state update, B=H=32, K=V=256, fp32.
// out[k,v] = g[k]*S[k,v] + cb[k]*(val[v] - kt[v]),
//   w[k] = g[k]*key[k], cb[k] = beta*key[k], kt[v] = sum_k w[k]*S[k,v].
//
// R14 = R10's wave-autonomous structure with the PROLOGUE INVERTED:
//   (a) issue scalar loads  (oldest in VMEM queue)
//   (b) issue all 32 tile loads
//   (c) stage scalars to LDS  -> compiler waits vmcnt(32): NO tile drain
//   (d) lgkm-only barrier     -> __syncthreads would vmcnt(0)-drain
// so the scalar HBM round-trip + barrier hide under tile-load streaming
// at every block-round boundary. Main body unchanged from R10: lane
// (r8,c8) owns 32 rows x one f32x4 col (128B chunks), in-wave butterfly
// kt, no barriers after (d).

#define KD 256
#define VD 256
#define VD4 (VD / 4)   // 64 f32x4 per row

typedef float f32x4 __attribute__((ext_vector_type(4)));

// barrier that drains LDS ops only -- in-flight global loads survive
__device__ __forceinline__ void lds_barrier() {
    asm volatile("s_waitcnt lgkmcnt(0)" ::: "memory");
    __builtin_amdgcn_s_barrier();
}

__global__ __launch_bounds__(256, 2)
void kda_update_kernel(const float* __restrict__ state,
                       const float* __restrict__ keys,
                       const float* __restrict__ values,
                       const float* __restrict__ gates,
                       const float* __restrict__ beta,
                       float* __restrict__ out)
{
    const int bid  = blockIdx.x;
    const int bh   = bid >> 1;          // (b,h) tile
    const int half = bid & 1;           // V half (cols 0-127 / 128-255)
    const size_t toff = (size_t)bh * (KD * VD);
    const f32x4* __restrict__ S4 = (const f32x4*)(state + toff);
    f32x4* __restrict__ O4 = (f32x4*)(out + toff);

    __shared__ float s_g[KD];   // alpha
    __shared__ float s_w[KD];   // alpha*key
    __shared__ float s_c[KD];   // beta*key

    const int t    = threadIdx.x;
    const int wv   = t >> 6;            // wave 0..3
    const int lane = t & 63;
    const int r8   = lane >> 3;         // row residue 0..7
    const int c8   = lane & 7;          // f32x4 col within wave's 8
    const int col  = half * 32 + wv * 8 + c8;   // this lane's f32x4 column

    // ---- (a) scalar loads FIRST (oldest in the in-order VMEM queue) ----
    const float g_t = gates[bh * KD + t];
    const float k_t = keys[bh * KD + t];
    const float b_b = beta[bh];
    __builtin_amdgcn_sched_barrier(0);   // pin: scalars issued before tiles

    // ---- (b) issue all 32 tile loads (128B chunks, rows r8+8j) ----
    f32x4 s[32];
#pragma unroll
    for (int j = 0; j < 32; ++j)
        s[j] = __builtin_nontemporal_load(&S4[(size_t)(r8 + 8 * j) * VD4 + col]);
    __builtin_amdgcn_sched_barrier(0);   // pin: tiles issued before staging

    // ---- (c) stage scalars (waits vmcnt(32): tile loads stay in flight) ----
    s_g[t] = g_t;
    s_w[t] = g_t * k_t;
    s_c[t] = b_b * k_t;

    // ---- (d) lgkm-only barrier (no vmcnt drain) ----
    lds_barrier();

    // ---- in-lane kt partial over this lane's 32 rows ----
    f32x4 p = (f32x4)(0.f);
#pragma unroll
    for (int j = 0; j < 32; ++j) {
        const float w = s_w[r8 + 8 * j];   // broadcast over c8
        p.x = fmaf(w, s[j].x, p.x);
        p.y = fmaf(w, s[j].y, p.y);
        p.z = fmaf(w, s[j].z, p.z);
        p.w = fmaf(w, s[j].w, p.w);
    }

    // ---- in-wave reduce over r8 (lane bits 3,4,5): 3 butterfly rounds ----
#pragma unroll
    for (int m = 8; m <= 32; m <<= 1) {
        p.x += __shfl_xor(p.x, m, 64);
        p.y += __shfl_xor(p.y, m, 64);
        p.z += __shfl_xor(p.z, m, 64);
        p.w += __shfl_xor(p.w, m, 64);
    }

    const f32x4 vv = ((const f32x4*)(values + (size_t)bh * VD))[col];
    f32x4 d;
    d.x = vv.x - p.x; d.y = vv.y - p.y;
    d.z = vv.z - p.z; d.w = vv.w - p.w;

    // ---- output: straight from registers, NT stores ----
#pragma unroll
    for (int j = 0; j < 32; ++j) {
        const int r = r8 + 8 * j;
        const float g  = s_g[r];
        const float cb = s_c[r];
        f32x4 o;
        o.x = fmaf(g, s[j].x, cb * d.x);
        o.y = fmaf(g, s[j].y, cb * d.y);
        o.z = fmaf(g, s[j].z, cb * d.z);
        o.w = fmaf(g, s[j].w, cb * d.w);
        __builtin_nontemporal_store(o, &O4[(size_t)r * VD4 + col]);
    }
}

extern "C" void kernel_launch(void* const* d_in, const int* in_sizes, int n_in,
                              void* d_out, int out_size, void* d_ws, size_t ws_size,
                              hipStream_t stream) {
    const float* state  = (const float*)d_in[0];
    const float* keys   = (const float*)d_in[1];
    const float* values = (const float*)d_in[2];
    const float* gates  = (const float*)d_in[3];
    const float* beta   = (const float*)d_in[4];
    float* out = (float*)d_out;

    dim3 grid(32 * 32 * 2);   // (b,h) x 2 V-halves
    dim3 block(256);
    hipLaunchKernelGGL(kda_update_kernel, grid, block, 0, stream,
                       state, keys, values, gates, beta, out);
}